// Round 6
// baseline (485.550 us; speedup 1.0000x reference)
//
#include <hip/hip_runtime.h>

#define H 128
#define ED 32
#define NLBL 256
#define NNODE_LBL 4096
#define LAYERS 3
#define SPAN 128          // nodes per bucket (dst >> 7); dstlocal fits 7 bits
#define MAXB 1024         // LDS cap for bucket arrays (nb = ceil(100000/128) = 782)
#define ELROWS (NLBL + 1) // +1 sentinel row (-1e30 -> relu contributes 0)

typedef short bf16x8 __attribute__((ext_vector_type(8)));
typedef float f32x4 __attribute__((ext_vector_type(4)));
typedef float f32x2 __attribute__((ext_vector_type(2)));

#define TWO48F 281474976710655.0f

static __device__ __forceinline__ float relu_f(float x) { return fmaxf(x, 0.f); }

static __device__ __forceinline__ unsigned short f2bf(float x) {
    unsigned u = __float_as_uint(x);
    return (unsigned short)((u + 0x7fffu + ((u >> 16) & 1u)) >> 16);
}

static __device__ __forceinline__ float bf2f(short b) {
    return __uint_as_float(((unsigned)(unsigned short)b) << 16);
}

static __device__ __forceinline__ f32x2 pk_add(f32x2 a, f32x2 b) {
    f32x2 d;
    asm("v_pk_add_f32 %0, %1, %2" : "=v"(d) : "v"(a), "v"(b));
    return d;
}

// ---------------- weight prep: fp32 [k][c] -> bf16 transposed [c][k] ----------------
// matrices: 0 = W_ref, 1..3 = W_a[l], 4..6 = W_b[l]

__global__ void split_weights_kernel(const float* __restrict__ W_ref,
                                     const float* __restrict__ W_a,
                                     const float* __restrict__ W_b,
                                     unsigned short* __restrict__ out) {
    int mat = blockIdx.y;
    const float* src = (mat == 0) ? W_ref
                     : (mat <= 3) ? W_a + (size_t)(mat - 1) * H * H
                                  : W_b + (size_t)(mat - 4) * H * H;
    int idx = blockIdx.x * 256 + threadIdx.x;      // [0, 16384)
    int k = idx >> 7, c = idx & 127;
    out[(size_t)mat * H * H + (size_t)c * H + k] = f2bf(src[idx]);
}

// ---------------- edge feature path (256 distinct labels only) ----------------

__global__ void edge_proj_kernel(const float* __restrict__ emb,
                                 const float* __restrict__ Pe1, const float* __restrict__ be1,
                                 const float* __restrict__ Pe2, const float* __restrict__ be2,
                                 float* __restrict__ e_proj) {
    int a = blockIdx.x, d = threadIdx.x;
    __shared__ float t[ED];
    float acc = be1[d];
    for (int k = 0; k < ED; ++k) acc = fmaf(emb[a * ED + k], Pe1[k * ED + d], acc);
    t[d] = fmaxf(acc, 0.f);
    __syncthreads();
    float acc2 = be2[d];
    for (int k = 0; k < ED; ++k) acc2 = fmaf(t[k], Pe2[k * ED + d], acc2);
    e_proj[a * ED + d] = acc2;
}

// el_tab in f32 (gather consumes f32; 131KB/layer, L2-resident); row NLBL = sentinel
__global__ void el_tab_kernel(const float* __restrict__ e_proj,
                              const float* __restrict__ W_lin, const float* __restrict__ b_lin,
                              float* __restrict__ el_tab) {
    int a = blockIdx.x, l = blockIdx.y, k = threadIdx.x;
    if (a == NLBL) {
        el_tab[((size_t)l * ELROWS + a) * H + k] = -1e30f;
        return;
    }
    float acc = b_lin[l * H + k];
    for (int d = 0; d < ED; ++d)
        acc = fmaf(e_proj[a * ED + d], W_lin[(l * ED + d) * H + k], acc);
    el_tab[((size_t)l * ELROWS + a) * H + k] = acc;
}

// ---------------- CSR build: per-node hist -> padded scan -> partition -> place --------
// Degrees padded to multiple of 8; sentinel edges (attr=NLBL) fill the pad so the gather
// inner loop is branch-free. Block-owned partition/place keep writes XCD-private (R5 fix).

__global__ void hist_kernel(const int* __restrict__ dst, int E, int* __restrict__ deg) {
    int e = blockIdx.x * blockDim.x + threadIdx.x;
    if (e < E) atomicAdd(&deg[dst[e]], 1);
}

__global__ void scan_block_sums(const int* __restrict__ deg, int n, int* __restrict__ bsum) {
    __shared__ int s[1024];
    int i = blockIdx.x * 1024 + threadIdx.x;
    s[threadIdx.x] = (i < n) ? ((deg[i] + 7) & ~7) : 0;
    __syncthreads();
    for (int off = 512; off > 0; off >>= 1) {
        if (threadIdx.x < off) s[threadIdx.x] += s[threadIdx.x + off];
        __syncthreads();
    }
    if (threadIdx.x == 0) bsum[blockIdx.x] = s[0];
}

__global__ void scan_bsum(int* __restrict__ bsum, int nbk,
                          int* __restrict__ totalA, int* __restrict__ totalB) {
    if (threadIdx.x == 0) {
        int run = 0;
        for (int b = 0; b < nbk; ++b) { int v = bsum[b]; bsum[b] = run; run += v; }
        *totalA = run;   // rowptr[N] = padded E
        *totalB = run;   // bbase[nb]
    }
}

__global__ void scan_final(const int* __restrict__ deg, int n,
                           const int* __restrict__ bsum, int* __restrict__ rowptr,
                           int* __restrict__ bbase, int* __restrict__ gcur) {
    __shared__ int s[1024];
    int i = blockIdx.x * 1024 + threadIdx.x;
    int v = (i < n) ? ((deg[i] + 7) & ~7) : 0;
    s[threadIdx.x] = v;
    __syncthreads();
    for (int off = 1; off < 1024; off <<= 1) {
        int add = (threadIdx.x >= off) ? s[threadIdx.x - off] : 0;
        __syncthreads();
        s[threadIdx.x] += add;
        __syncthreads();
    }
    if (i < n) {
        int ex = bsum[blockIdx.x] + s[threadIdx.x] - v;   // exclusive padded prefix
        rowptr[i] = ex;
        if ((i & (SPAN - 1)) == 0) {
            bbase[i >> 7] = ex;
            gcur[i >> 7] = ex;
        }
    }
}

// entry = src | attr<<17 | dstlocal<<25  (17 + 8 + 7 = 32 bits)
__global__ __launch_bounds__(256) void partition_kernel(
    const int* __restrict__ src, const int* __restrict__ dst,
    const int* __restrict__ attr, int E, int nb,
    int* __restrict__ gcur, unsigned* __restrict__ ebuf) {
    __shared__ int lh[MAXB], gofs[MAXB], lc[MAXB];
    const int t = threadIdx.x;
    const int e0 = blockIdx.x * 4096;
    const int e1 = min(e0 + 4096, E);
    for (int i = t; i < nb; i += 256) { lh[i] = 0; lc[i] = 0; }
    __syncthreads();
    for (int e = e0 + t; e < e1; e += 256) atomicAdd(&lh[dst[e] >> 7], 1);
    __syncthreads();
    for (int i = t; i < nb; i += 256)
        if (lh[i]) gofs[i] = atomicAdd(&gcur[i], lh[i]);
    __syncthreads();
    for (int e = e0 + t; e < e1; e += 256) {
        int d = dst[e];
        int b = d >> 7;
        int slot = gofs[b] + atomicAdd(&lc[b], 1);
        ebuf[slot] = (unsigned)src[e] | ((unsigned)attr[e] << 17) | ((unsigned)(d & 127) << 25);
    }
}

// one block per bucket: place entries at padded per-node offsets, stamp sentinels in pad
__global__ __launch_bounds__(128) void place_kernel(
    const unsigned* __restrict__ ebuf, const int* __restrict__ bbase,
    const int* __restrict__ gcur, const int* __restrict__ rowptr,
    int n, int* __restrict__ sorted) {
    __shared__ int rp[SPAN + 1], lc[SPAN];
    const int b = blockIdx.x, t = threadIdx.x;   // 128 threads
    int node = b * SPAN + t;
    rp[t] = rowptr[min(node, n)];
    if (t == 0) rp[SPAN] = rowptr[min(b * SPAN + SPAN, n)];
    lc[t] = 0;
    __syncthreads();
    const int base = bbase[b], rawend = gcur[b];
    for (int e = base + t; e < rawend; e += SPAN) {
        unsigned p = ebuf[e];
        int dl = p >> 25;
        int pos = rp[dl] + atomicAdd(&lc[dl], 1);
        sorted[pos] = (int)(p & 0x1FFFFFFu);
    }
    __syncthreads();
    if (node < n) {
        int s0 = rp[t] + lc[t], s1 = rp[t + 1];
        for (int pos = s0; pos < s1; ++pos)
            sorted[pos] = (NLBL << 17);          // sentinel: src 0, el row NLBL (-1e30)
    }
}

// ---------------- per-node aggregation: z = h + sum relu(h[src] + el[attr]) ----------------
// bf16 h, f32 el. One wave per node; 8 edges in flight (2 chunks x 4 groups x 16 lanes);
// branch-free (padded+sentinel CSR); packed f32 adds; 32-bit addressing.

static __device__ __forceinline__ void edge_accum(
    int p, const unsigned short* __restrict__ hB, const float* __restrict__ eB,
    f32x2& a0, f32x2& a1, f32x2& a2, f32x2& a3) {
    unsigned so = ((unsigned)(p & 131071)) << 7;
    unsigned ao = ((unsigned)p >> 17) << 7;
    int4 hu = *(const int4*)(hB + so);
    float4 e0 = *(const float4*)(eB + ao);
    float4 e1 = *(const float4*)(eB + ao + 4);
    f32x2 t;
    t = pk_add((f32x2){__uint_as_float(((unsigned)hu.x) << 16),
                       __uint_as_float(((unsigned)hu.x) & 0xffff0000u)},
               (f32x2){e0.x, e0.y});
    t[0] = fmaxf(t[0], 0.f); t[1] = fmaxf(t[1], 0.f);
    a0 = pk_add(a0, t);
    t = pk_add((f32x2){__uint_as_float(((unsigned)hu.y) << 16),
                       __uint_as_float(((unsigned)hu.y) & 0xffff0000u)},
               (f32x2){e0.z, e0.w});
    t[0] = fmaxf(t[0], 0.f); t[1] = fmaxf(t[1], 0.f);
    a1 = pk_add(a1, t);
    t = pk_add((f32x2){__uint_as_float(((unsigned)hu.z) << 16),
                       __uint_as_float(((unsigned)hu.z) & 0xffff0000u)},
               (f32x2){e1.x, e1.y});
    t[0] = fmaxf(t[0], 0.f); t[1] = fmaxf(t[1], 0.f);
    a2 = pk_add(a2, t);
    t = pk_add((f32x2){__uint_as_float(((unsigned)hu.w) << 16),
                       __uint_as_float(((unsigned)hu.w) & 0xffff0000u)},
               (f32x2){e1.z, e1.w});
    t[0] = fmaxf(t[0], 0.f); t[1] = fmaxf(t[1], 0.f);
    a3 = pk_add(a3, t);
}

__global__ __launch_bounds__(256) void gather_kernel(
    const unsigned short* __restrict__ hbf, const int* __restrict__ rowptr,
    const int* __restrict__ sorted, const float* __restrict__ el,
    int n, unsigned short* __restrict__ z) {
    int wave = threadIdx.x >> 6;
    int lane = threadIdx.x & 63;
    int i = blockIdx.x * 4 + wave;
    if (i >= n) return;
    int beg = rowptr[i], end = rowptr[i + 1];
    int gg = lane >> 4, m = lane & 15;
    const unsigned short* hB = hbf + m * 8;
    const float* eB = el + m * 8;
    f32x2 a0 = {0.f, 0.f}, a1 = a0, a2 = a0, a3 = a0;
    for (int e = beg; e < end; e += 8) {
        int pA = sorted[e + gg];
        int pB = sorted[e + 4 + gg];
        edge_accum(pA, hB, eB, a0, a1, a2, a3);
        edge_accum(pB, hB, eB, a0, a1, a2, a3);
    }
    float r[8];
    r[0] = a0[0]; r[1] = a0[1]; r[2] = a1[0]; r[3] = a1[1];
    r[4] = a2[0]; r[5] = a2[1]; r[6] = a3[0]; r[7] = a3[1];
#pragma unroll
    for (int j = 0; j < 8; ++j) {
        r[j] += __shfl_xor(r[j], 16, 64);
        r[j] += __shfl_xor(r[j], 32, 64);
    }
    if (gg == 0) {
        bf16x8 hv = *(const bf16x8*)(hbf + (unsigned)i * H + m * 8);
        bf16x8 o;
#pragma unroll
        for (int j = 0; j < 8; ++j)
            o[j] = (short)f2bf(bf2f(hv[j]) + r[j]);
        *(bf16x8*)(z + (unsigned)i * H + m * 8) = o;
    }
}

// ---------------- MFMA fused MLP: h = relu(relu(z@Wa+ba)@Wb+bb), bf16 in, bf16/fp32 out ----

__global__ __launch_bounds__(128) void mlp_mfma_kernel(
    const unsigned short* __restrict__ z,
    const unsigned short* __restrict__ WA, const float* __restrict__ ba,
    const unsigned short* __restrict__ WB, const float* __restrict__ bb,
    int n, unsigned short* __restrict__ hbf, float* __restrict__ hf32) {
    __shared__ short sT[2][32 * H];
    const int t = threadIdx.x;
    const int w = t >> 6, lane = t & 63;
    const int m = lane & 15, g = lane >> 4;
    const int nb = blockIdx.x * 64 + w * 32;

    bf16x8 za[2][4];
#pragma unroll
    for (int rt = 0; rt < 2; ++rt) {
        int row = nb + 16 * rt + m; if (row >= n) row = n - 1;
        const unsigned short* zr = z + (size_t)row * H;
#pragma unroll
        for (int ks = 0; ks < 4; ++ks)
            za[rt][ks] = *(const bf16x8*)(zr + 32 * ks + 8 * g);
    }

#pragma unroll 1
    for (int ct = 0; ct < 8; ++ct) {
        float bias = ba[16 * ct + m];
        f32x4 c1[2];
        c1[0] = (f32x4){bias, bias, bias, bias};
        c1[1] = c1[0];
#pragma unroll
        for (int ks = 0; ks < 4; ++ks) {
            bf16x8 bh = *(const bf16x8*)(WA + (size_t)(16 * ct + m) * H + 32 * ks + 8 * g);
            c1[0] = __builtin_amdgcn_mfma_f32_16x16x32_bf16(za[0][ks], bh, c1[0], 0, 0, 0);
            c1[1] = __builtin_amdgcn_mfma_f32_16x16x32_bf16(za[1][ks], bh, c1[1], 0, 0, 0);
        }
#pragma unroll
        for (int rt = 0; rt < 2; ++rt) {
#pragma unroll
            for (int r = 0; r < 4; ++r) {
                float v = fmaxf(c1[rt][r], 0.f);
                int nl = 16 * rt + 4 * g + r;
                int kk = (16 * ct + m) ^ (8 * (nl & 7));
                sT[w][nl * H + kk] = (short)f2bf(v);
            }
        }
    }

    __syncthreads();

    f32x4 c2[2][8];
#pragma unroll
    for (int ct = 0; ct < 8; ++ct) {
        float bias = bb[16 * ct + m];
        c2[0][ct] = (f32x4){bias, bias, bias, bias};
        c2[1][ct] = c2[0][ct];
    }
#pragma unroll 1
    for (int ks = 0; ks < 4; ++ks) {
        bf16x8 ta[2];
#pragma unroll
        for (int rt = 0; rt < 2; ++rt) {
            int nl = 16 * rt + m;
            int kk = (32 * ks + 8 * g) ^ (8 * (nl & 7));
            ta[rt] = *(const bf16x8*)&sT[w][nl * H + kk];
        }
#pragma unroll
        for (int ct = 0; ct < 8; ++ct) {
            bf16x8 bh = *(const bf16x8*)(WB + (size_t)(16 * ct + m) * H + 32 * ks + 8 * g);
            c2[0][ct] = __builtin_amdgcn_mfma_f32_16x16x32_bf16(ta[0], bh, c2[0][ct], 0, 0, 0);
            c2[1][ct] = __builtin_amdgcn_mfma_f32_16x16x32_bf16(ta[1], bh, c2[1][ct], 0, 0, 0);
        }
    }

    if (hf32) {
#pragma unroll
        for (int rt = 0; rt < 2; ++rt)
#pragma unroll
            for (int r = 0; r < 4; ++r) {
                int node = nb + 16 * rt + 4 * g + r;
                if (node < n) {
                    float* hp = hf32 + (size_t)node * H + m;
#pragma unroll
                    for (int ct = 0; ct < 8; ++ct)
                        hp[16 * ct] = fmaxf(c2[rt][ct][r], 0.f);
                }
            }
    } else {
#pragma unroll
        for (int rt = 0; rt < 2; ++rt)
#pragma unroll
            for (int r = 0; r < 4; ++r) {
                int node = nb + 16 * rt + 4 * g + r;
                if (node < n) {
                    unsigned short* hp = hbf + (size_t)node * H + m;
#pragma unroll
                    for (int ct = 0; ct < 8; ++ct)
                        hp[16 * ct] = f2bf(fmaxf(c2[rt][ct][r], 0.f));
                }
            }
    }
}

// ---------------- input proj (rank-1 first layer) + refine matmul + node emb, MFMA ----------------

__global__ __launch_bounds__(128) void input_proj_mfma_kernel(
    const float* __restrict__ nf,
    const float* __restrict__ W_in, const float* __restrict__ b_in,
    const unsigned short* __restrict__ WR, const float* __restrict__ b_ref,
    const float* __restrict__ node_emb,
    int n, unsigned short* __restrict__ hbf) {
    __shared__ float sx[64];
    __shared__ int sid[64];
    const int t = threadIdx.x;
    const int w = t >> 6, lane = t & 63;
    const int m = lane & 15, g = lane >> 4;
    const int nb0 = blockIdx.x * 64;
    if (t < 64) {
        int node = nb0 + t;
        float xv = (node < n) ? nf[node] : 0.f;
        sx[t] = fminf(fmaxf(xv / TWO48F, 0.f), 1.f);
        sid[t] = ((int)xv) & (NNODE_LBL - 1);
    }
    __syncthreads();
    const int nb = nb0 + w * 32;

    bf16x8 ta[2][4];
#pragma unroll
    for (int rt = 0; rt < 2; ++rt) {
        float xv = sx[w * 32 + 16 * rt + m];
#pragma unroll
        for (int ks = 0; ks < 4; ++ks) {
            float4 w0 = *(const float4*)(W_in + 32 * ks + 8 * g);
            float4 w1 = *(const float4*)(W_in + 32 * ks + 8 * g + 4);
            float4 b0 = *(const float4*)(b_in + 32 * ks + 8 * g);
            float4 b1 = *(const float4*)(b_in + 32 * ks + 8 * g + 4);
            bf16x8 v;
            v[0] = (short)f2bf(relu_f(fmaf(xv, w0.x, b0.x)));
            v[1] = (short)f2bf(relu_f(fmaf(xv, w0.y, b0.y)));
            v[2] = (short)f2bf(relu_f(fmaf(xv, w0.z, b0.z)));
            v[3] = (short)f2bf(relu_f(fmaf(xv, w0.w, b0.w)));
            v[4] = (short)f2bf(relu_f(fmaf(xv, w1.x, b1.x)));
            v[5] = (short)f2bf(relu_f(fmaf(xv, w1.y, b1.y)));
            v[6] = (short)f2bf(relu_f(fmaf(xv, w1.z, b1.z)));
            v[7] = (short)f2bf(relu_f(fmaf(xv, w1.w, b1.w)));
            ta[rt][ks] = v;
        }
    }

    f32x4 c2[2][8];
#pragma unroll
    for (int ct = 0; ct < 8; ++ct) {
        float bias = b_ref[16 * ct + m];
        c2[0][ct] = (f32x4){bias, bias, bias, bias};
        c2[1][ct] = c2[0][ct];
    }
#pragma unroll
    for (int ct = 0; ct < 8; ++ct) {
#pragma unroll
        for (int ks = 0; ks < 4; ++ks) {
            bf16x8 bh = *(const bf16x8*)(WR + (size_t)(16 * ct + m) * H + 32 * ks + 8 * g);
            c2[0][ct] = __builtin_amdgcn_mfma_f32_16x16x32_bf16(ta[0][ks], bh, c2[0][ct], 0, 0, 0);
            c2[1][ct] = __builtin_amdgcn_mfma_f32_16x16x32_bf16(ta[1][ks], bh, c2[1][ct], 0, 0, 0);
        }
    }

#pragma unroll
    for (int rt = 0; rt < 2; ++rt)
#pragma unroll
        for (int r = 0; r < 4; ++r) {
            int node = nb + 16 * rt + 4 * g + r;
            if (node < n) {
                int id = sid[w * 32 + 16 * rt + 4 * g + r];
                const float* ep = node_emb + (size_t)id * H + m;
                unsigned short* hp = hbf + (size_t)node * H + m;
#pragma unroll
                for (int ct = 0; ct < 8; ++ct)
                    hp[16 * ct] = f2bf(c2[rt][ct][r] + ep[16 * ct]);
            }
        }
}

// ---------------- host launcher ----------------

extern "C" void kernel_launch(void* const* d_in, const int* in_sizes, int n_in,
                              void* d_out, int out_size, void* d_ws, size_t ws_size,
                              hipStream_t stream) {
    const float* nf       = (const float*)d_in[0];
    const int*   eidx     = (const int*)d_in[1];
    const int*   eattr    = (const int*)d_in[2];
    const float* W_in     = (const float*)d_in[3];
    const float* b_in     = (const float*)d_in[4];
    const float* W_ref    = (const float*)d_in[5];
    const float* b_ref    = (const float*)d_in[6];
    const float* node_emb = (const float*)d_in[7];
    const float* edge_emb = (const float*)d_in[8];
    const float* Pe1      = (const float*)d_in[9];
    const float* be1      = (const float*)d_in[10];
    const float* Pe2      = (const float*)d_in[11];
    const float* be2      = (const float*)d_in[12];
    const float* W_lin    = (const float*)d_in[13];
    const float* b_lin    = (const float*)d_in[14];
    const float* W_a      = (const float*)d_in[15];
    const float* b_a      = (const float*)d_in[16];
    const float* W_b      = (const float*)d_in[17];
    const float* b_b      = (const float*)d_in[18];

    const int N = in_sizes[0];
    const int E = in_sizes[2];
    const int* src = eidx;
    const int* dst = eidx + E;
    const int nb = (N + SPAN - 1) / SPAN;     // 782 buckets
    const int NBK = (N + 1023) / 1024;        // scan blocks
    const size_t EPAD = (size_t)E + 8 * (size_t)N + 64;

    char* ws = (char*)d_ws;
    size_t off = 0;
    auto carve = [&](size_t bytes) -> void* {
        void* p = (void*)(ws + off);
        off = (off + bytes + 511) & ~(size_t)511;
        return p;
    };
    unsigned short* z      = (unsigned short*)carve((size_t)N * H * sizeof(unsigned short));
    unsigned short* hbf    = (unsigned short*)carve((size_t)N * H * sizeof(unsigned short));
    unsigned* ebuf  = (unsigned*)carve(EPAD * sizeof(unsigned));
    int*   sorted = (int*)carve(EPAD * sizeof(int));
    int*   rowptr = (int*)carve((size_t)(N + 1) * sizeof(int));
    int*   deg    = (int*)carve((size_t)N * sizeof(int));
    int*   bsum   = (int*)carve((size_t)NBK * sizeof(int));
    int*   bbase  = (int*)carve((size_t)(nb + 1) * sizeof(int));
    int*   gcur   = (int*)carve((size_t)nb * sizeof(int));
    float* el_tab = (float*)carve((size_t)LAYERS * ELROWS * H * sizeof(float));
    float* e_proj = (float*)carve((size_t)NLBL * ED * sizeof(float));
    unsigned short* wsp = (unsigned short*)carve((size_t)7 * H * H * sizeof(unsigned short));
    float* h_out = (float*)d_out;

    // weight prep (bf16, transposed to [col][k])
    split_weights_kernel<<<dim3(64, 7), 256, 0, stream>>>(W_ref, W_a, W_b, wsp);

    // CSR build: per-node hist -> padded scan (rowptr, bucket bases) -> partition -> place
    hipMemsetAsync(deg, 0, (size_t)N * sizeof(int), stream);
    hist_kernel<<<(E + 255) / 256, 256, 0, stream>>>(dst, E, deg);
    scan_block_sums<<<NBK, 1024, 0, stream>>>(deg, N, bsum);
    scan_bsum<<<1, 64, 0, stream>>>(bsum, NBK, rowptr + N, bbase + nb);
    scan_final<<<NBK, 1024, 0, stream>>>(deg, N, bsum, rowptr, bbase, gcur);
    partition_kernel<<<(E + 4095) / 4096, 256, 0, stream>>>(src, dst, eattr, E, nb, gcur, ebuf);
    place_kernel<<<nb, SPAN, 0, stream>>>(ebuf, bbase, gcur, rowptr, N, sorted);

    // edge feature tables (256 labels + sentinel row)
    edge_proj_kernel<<<NLBL, ED, 0, stream>>>(edge_emb, Pe1, be1, Pe2, be2, e_proj);
    el_tab_kernel<<<dim3(ELROWS, LAYERS), H, 0, stream>>>(e_proj, W_lin, b_lin, el_tab);

    // node path
    const int gridMM = (N + 63) / 64;
    input_proj_mfma_kernel<<<gridMM, 128, 0, stream>>>(
        nf, W_in, b_in, wsp, b_ref, node_emb, N, hbf);

    for (int l = 0; l < LAYERS; ++l) {
        gather_kernel<<<(N + 3) / 4, 256, 0, stream>>>(
            hbf, rowptr, sorted, el_tab + (size_t)l * ELROWS * H, N, z);
        mlp_mfma_kernel<<<gridMM, 128, 0, stream>>>(
            z,
            wsp + (size_t)(1 + l) * H * H, b_a + (size_t)l * H,
            wsp + (size_t)(4 + l) * H * H, b_b + (size_t)l * H,
            N, hbf, (l == LAYERS - 1) ? h_out : nullptr);
    }
}

// Round 8
// 420.999 us; speedup vs baseline: 1.1533x; 1.1533x over previous
//
#include <hip/hip_runtime.h>

#define H 128
#define ED 32
#define NLBL 256
#define NNODE_LBL 4096
#define LAYERS 3
#define SPAN 128          // nodes per bucket (dst >> 7); dstlocal fits 7 bits
#define MAXB 1024         // LDS cap for bucket arrays (nb = ceil(100000/128) = 782)
#define ELROWS (NLBL + 1) // +1 sentinel row (-1e30 -> relu contributes 0)

typedef short bf16x8 __attribute__((ext_vector_type(8)));
typedef float f32x4 __attribute__((ext_vector_type(4)));
typedef float f32x2 __attribute__((ext_vector_type(2)));

#define TWO48F 281474976710655.0f

static __device__ __forceinline__ float relu_f(float x) { return fmaxf(x, 0.f); }

static __device__ __forceinline__ unsigned short f2bf(float x) {
    unsigned u = __float_as_uint(x);
    return (unsigned short)((u + 0x7fffu + ((u >> 16) & 1u)) >> 16);
}

static __device__ __forceinline__ float bf2f(short b) {
    return __uint_as_float(((unsigned)(unsigned short)b) << 16);
}

// ---------------- weight prep: fp32 [k][c] -> bf16 transposed [c][k] ----------------
// matrices: 0 = W_ref, 1..3 = W_a[l], 4..6 = W_b[l]

__global__ void split_weights_kernel(const float* __restrict__ W_ref,
                                     const float* __restrict__ W_a,
                                     const float* __restrict__ W_b,
                                     unsigned short* __restrict__ out) {
    int mat = blockIdx.y;
    const float* src = (mat == 0) ? W_ref
                     : (mat <= 3) ? W_a + (size_t)(mat - 1) * H * H
                                  : W_b + (size_t)(mat - 4) * H * H;
    int idx = blockIdx.x * 256 + threadIdx.x;      // [0, 16384)
    int k = idx >> 7, c = idx & 127;
    out[(size_t)mat * H * H + (size_t)c * H + k] = f2bf(src[idx]);
}

// ---------------- edge feature path (256 distinct labels only) ----------------

__global__ void edge_proj_kernel(const float* __restrict__ emb,
                                 const float* __restrict__ Pe1, const float* __restrict__ be1,
                                 const float* __restrict__ Pe2, const float* __restrict__ be2,
                                 float* __restrict__ e_proj) {
    int a = blockIdx.x, d = threadIdx.x;
    __shared__ float t[ED];
    float acc = be1[d];
    for (int k = 0; k < ED; ++k) acc = fmaf(emb[a * ED + k], Pe1[k * ED + d], acc);
    t[d] = fmaxf(acc, 0.f);
    __syncthreads();
    float acc2 = be2[d];
    for (int k = 0; k < ED; ++k) acc2 = fmaf(t[k], Pe2[k * ED + d], acc2);
    e_proj[a * ED + d] = acc2;
}

// el_tab in f32 (gather consumes f32; L2-resident); row NLBL = sentinel
__global__ void el_tab_kernel(const float* __restrict__ e_proj,
                              const float* __restrict__ W_lin, const float* __restrict__ b_lin,
                              float* __restrict__ el_tab) {
    int a = blockIdx.x, l = blockIdx.y, k = threadIdx.x;
    if (a == NLBL) {
        el_tab[((size_t)l * ELROWS + a) * H + k] = -1e30f;
        return;
    }
    float acc = b_lin[l * H + k];
    for (int d = 0; d < ED; ++d)
        acc = fmaf(e_proj[a * ED + d], W_lin[(l * ED + d) * H + k], acc);
    el_tab[((size_t)l * ELROWS + a) * H + k] = acc;
}

// ---------------- CSR build: bucket hist -> slack scan -> partition -> place ----------
// Buckets get cnt + 3*SPAN slack; place derives per-node counts, computes the pad-to-4
// prefix locally, writes rowptr AND rowend (slack leaves inter-bucket gaps, so the end
// of node i is NOT rowptr[i+1] -- that was R7's bug). Block-owned writes stay XCD-private.

__global__ __launch_bounds__(256) void bucket_hist_kernel(
    const int* __restrict__ dst, int E, int nb, int* __restrict__ bcnt) {
    __shared__ int lh[MAXB];
    for (int i = threadIdx.x; i < nb; i += 256) lh[i] = 0;
    __syncthreads();
    for (int e = blockIdx.x * 256 + threadIdx.x; e < E; e += gridDim.x * 256)
        atomicAdd(&lh[dst[e] >> 7], 1);
    __syncthreads();
    for (int i = threadIdx.x; i < nb; i += 256)
        if (lh[i]) atomicAdd(&bcnt[i], lh[i]);
}

__global__ void bucket_scan_kernel(const int* __restrict__ bcnt, int nb,
                                   int* __restrict__ bbase, int* __restrict__ gcur) {
    __shared__ int s[MAXB];
    int t = threadIdx.x;                       // 1024 threads
    s[t] = (t < nb) ? (bcnt[t] + 3 * SPAN) : 0;   // max pad 3/node
    __syncthreads();
    for (int off = 1; off < MAXB; off <<= 1) {
        int v = (t >= off) ? s[t - off] : 0;
        __syncthreads();
        s[t] += v;
        __syncthreads();
    }
    if (t < nb) {
        int ex = (t == 0) ? 0 : s[t - 1];
        bbase[t] = ex;
        gcur[t] = ex;
    }
    if (t == nb) bbase[nb] = s[nb - 1];
}

// entry = src | attr<<17 | dstlocal<<25  (17 + 8 + 7 = 32 bits)
__global__ __launch_bounds__(256) void partition_kernel(
    const int* __restrict__ src, const int* __restrict__ dst,
    const int* __restrict__ attr, int E, int nb,
    int* __restrict__ gcur, unsigned* __restrict__ ebuf) {
    __shared__ int lh[MAXB], gofs[MAXB], lc[MAXB];
    const int t = threadIdx.x;
    const int e0 = blockIdx.x * 4096;
    const int e1 = min(e0 + 4096, E);
    for (int i = t; i < nb; i += 256) { lh[i] = 0; lc[i] = 0; }
    __syncthreads();
    for (int e = e0 + t; e < e1; e += 256) atomicAdd(&lh[dst[e] >> 7], 1);
    __syncthreads();
    for (int i = t; i < nb; i += 256)
        if (lh[i]) gofs[i] = atomicAdd(&gcur[i], lh[i]);
    __syncthreads();
    for (int e = e0 + t; e < e1; e += 256) {
        int d = dst[e];
        int b = d >> 7;
        int slot = gofs[b] + atomicAdd(&lc[b], 1);
        ebuf[slot] = (unsigned)src[e] | ((unsigned)attr[e] << 17) | ((unsigned)(d & 127) << 25);
    }
}

// one block per bucket: count -> padded prefix -> rowptr/rowend + place + sentinels
__global__ __launch_bounds__(128) void place_kernel(
    const unsigned* __restrict__ ebuf, const int* __restrict__ bbase,
    const int* __restrict__ gcur, int n,
    int* __restrict__ rowptr, int* __restrict__ rowend, int* __restrict__ sorted) {
    __shared__ int rp[SPAN], lc[SPAN], sc[SPAN];
    const int b = blockIdx.x, t = threadIdx.x;   // 128 threads
    const int base = bbase[b], rawend = gcur[b];
    lc[t] = 0;
    __syncthreads();
    for (int e = base + t; e < rawend; e += SPAN)
        atomicAdd(&lc[ebuf[e] >> 25], 1);
    __syncthreads();
    const int cnt = lc[t];
    const int pad = (cnt + 3) & ~3;
    sc[t] = pad;
    __syncthreads();
    for (int off = 1; off < SPAN; off <<= 1) {
        int v = (t >= off) ? sc[t - off] : 0;
        __syncthreads();
        sc[t] += v;
        __syncthreads();
    }
    const int mystart = base + sc[t] - pad;
    rp[t] = mystart;
    lc[t] = 0;
    const int node = b * SPAN + t;
    if (node < n) {
        rowptr[node] = mystart;
        rowend[node] = mystart + pad;
    }
    __syncthreads();
    for (int e = base + t; e < rawend; e += SPAN) {
        unsigned p = ebuf[e];
        int dl = p >> 25;
        int pos = rp[dl] + atomicAdd(&lc[dl], 1);
        sorted[pos] = (int)(p & 0x1FFFFFFu);
    }
    __syncthreads();
    if (node < n)
        for (int pos = mystart + cnt; pos < mystart + pad; ++pos)
            sorted[pos] = (NLBL << 17);          // sentinel: src 0, el row NLBL (-1e30)
}

// ---------------- per-node aggregation: z = h + sum relu(h[src] + el[attr]) ----------------
// bf16 h, f32 el. One wave per node; 4-8 edges in flight (4 groups x 16 lanes);
// branch-free inner body (pad-to-4 + uniform tail); vector-IR f32x2 -> v_pk_* ops.

static __device__ __forceinline__ void edge_acc(
    unsigned p, const unsigned* __restrict__ hB, const float* __restrict__ eB,
    f32x2& a0, f32x2& a1, f32x2& a2, f32x2& a3) {
    unsigned so = (p & 131071u) << 6;   // h row stride: 64 u32
    unsigned ao = (p >> 17) << 7;       // el row stride: 128 f32
    uint4 hu = *(const uint4*)(hB + so);
    float4 e0 = *(const float4*)(eB + ao);
    float4 e1 = *(const float4*)(eB + ao + 4);
    const f32x2 zero = {0.f, 0.f};
    f32x2 h, s;
    h[0] = __uint_as_float(hu.x << 16); h[1] = __uint_as_float(hu.x & 0xffff0000u);
    s = h + (f32x2){e0.x, e0.y};
    a0 = a0 + __builtin_elementwise_max(s, zero);
    h[0] = __uint_as_float(hu.y << 16); h[1] = __uint_as_float(hu.y & 0xffff0000u);
    s = h + (f32x2){e0.z, e0.w};
    a1 = a1 + __builtin_elementwise_max(s, zero);
    h[0] = __uint_as_float(hu.z << 16); h[1] = __uint_as_float(hu.z & 0xffff0000u);
    s = h + (f32x2){e1.x, e1.y};
    a2 = a2 + __builtin_elementwise_max(s, zero);
    h[0] = __uint_as_float(hu.w << 16); h[1] = __uint_as_float(hu.w & 0xffff0000u);
    s = h + (f32x2){e1.z, e1.w};
    a3 = a3 + __builtin_elementwise_max(s, zero);
}

__global__ __launch_bounds__(256) void gather_kernel(
    const unsigned short* __restrict__ hbf, const int* __restrict__ rowptr,
    const int* __restrict__ rowend, const int* __restrict__ sorted,
    const float* __restrict__ el, int n, unsigned short* __restrict__ z) {
    int wave = threadIdx.x >> 6;
    int lane = threadIdx.x & 63;
    int i = blockIdx.x * 4 + wave;
    if (i >= n) return;
    int beg = rowptr[i], end = rowend[i];
    int gg = lane >> 4, m = lane & 15;
    const unsigned* hB = (const unsigned*)hbf + m * 4;
    const float* eB = el + m * 8;
    f32x2 a0 = {0.f, 0.f}, a1 = a0, a2 = a0, a3 = a0;
    int e = beg;
    for (; e + 8 <= end; e += 8) {
        unsigned pA = (unsigned)sorted[e + gg];
        unsigned pB = (unsigned)sorted[e + 4 + gg];
        edge_acc(pA, hB, eB, a0, a1, a2, a3);
        edge_acc(pB, hB, eB, a0, a1, a2, a3);
    }
    if (e < end) {
        unsigned pA = (unsigned)sorted[e + gg];
        edge_acc(pA, hB, eB, a0, a1, a2, a3);
    }
    float r[8];
    r[0] = a0[0]; r[1] = a0[1]; r[2] = a1[0]; r[3] = a1[1];
    r[4] = a2[0]; r[5] = a2[1]; r[6] = a3[0]; r[7] = a3[1];
#pragma unroll
    for (int j = 0; j < 8; ++j) {
        r[j] += __shfl_xor(r[j], 16, 64);
        r[j] += __shfl_xor(r[j], 32, 64);
    }
    if (gg == 0) {
        bf16x8 hv = *(const bf16x8*)(hbf + (unsigned)i * H + m * 8);
        bf16x8 o;
#pragma unroll
        for (int j = 0; j < 8; ++j)
            o[j] = (short)f2bf(bf2f(hv[j]) + r[j]);
        *(bf16x8*)(z + (unsigned)i * H + m * 8) = o;
    }
}

// ---------------- MFMA fused MLP: h = relu(relu(z@Wa+ba)@Wb+bb), bf16 in, bf16/fp32 out ----

__global__ __launch_bounds__(128) void mlp_mfma_kernel(
    const unsigned short* __restrict__ z,
    const unsigned short* __restrict__ WA, const float* __restrict__ ba,
    const unsigned short* __restrict__ WB, const float* __restrict__ bb,
    int n, unsigned short* __restrict__ hbf, float* __restrict__ hf32) {
    __shared__ short sT[2][32 * H];
    const int t = threadIdx.x;
    const int w = t >> 6, lane = t & 63;
    const int m = lane & 15, g = lane >> 4;
    const int nb = blockIdx.x * 64 + w * 32;

    bf16x8 za[2][4];
#pragma unroll
    for (int rt = 0; rt < 2; ++rt) {
        int row = nb + 16 * rt + m; if (row >= n) row = n - 1;
        const unsigned short* zr = z + (size_t)row * H;
#pragma unroll
        for (int ks = 0; ks < 4; ++ks)
            za[rt][ks] = *(const bf16x8*)(zr + 32 * ks + 8 * g);
    }

#pragma unroll 2
    for (int ct = 0; ct < 8; ++ct) {
        float bias = ba[16 * ct + m];
        f32x4 c1[2];
        c1[0] = (f32x4){bias, bias, bias, bias};
        c1[1] = c1[0];
#pragma unroll
        for (int ks = 0; ks < 4; ++ks) {
            bf16x8 bh = *(const bf16x8*)(WA + (size_t)(16 * ct + m) * H + 32 * ks + 8 * g);
            c1[0] = __builtin_amdgcn_mfma_f32_16x16x32_bf16(za[0][ks], bh, c1[0], 0, 0, 0);
            c1[1] = __builtin_amdgcn_mfma_f32_16x16x32_bf16(za[1][ks], bh, c1[1], 0, 0, 0);
        }
#pragma unroll
        for (int rt = 0; rt < 2; ++rt) {
#pragma unroll
            for (int r = 0; r < 4; ++r) {
                float v = fmaxf(c1[rt][r], 0.f);
                int nl = 16 * rt + 4 * g + r;
                int kk = (16 * ct + m) ^ (8 * (nl & 7));
                sT[w][nl * H + kk] = (short)f2bf(v);
            }
        }
    }

    __syncthreads();

    f32x4 c2[2][8];
#pragma unroll
    for (int ct = 0; ct < 8; ++ct) {
        float bias = bb[16 * ct + m];
        c2[0][ct] = (f32x4){bias, bias, bias, bias};
        c2[1][ct] = c2[0][ct];
    }
#pragma unroll 2
    for (int ks = 0; ks < 4; ++ks) {
        bf16x8 ta[2];
#pragma unroll
        for (int rt = 0; rt < 2; ++rt) {
            int nl = 16 * rt + m;
            int kk = (32 * ks + 8 * g) ^ (8 * (nl & 7));
            ta[rt] = *(const bf16x8*)&sT[w][nl * H + kk];
        }
#pragma unroll
        for (int ct = 0; ct < 8; ++ct) {
            bf16x8 bh = *(const bf16x8*)(WB + (size_t)(16 * ct + m) * H + 32 * ks + 8 * g);
            c2[0][ct] = __builtin_amdgcn_mfma_f32_16x16x32_bf16(ta[0], bh, c2[0][ct], 0, 0, 0);
            c2[1][ct] = __builtin_amdgcn_mfma_f32_16x16x32_bf16(ta[1], bh, c2[1][ct], 0, 0, 0);
        }
    }

    if (hf32) {
#pragma unroll
        for (int rt = 0; rt < 2; ++rt)
#pragma unroll
            for (int r = 0; r < 4; ++r) {
                int node = nb + 16 * rt + 4 * g + r;
                if (node < n) {
                    float* hp = hf32 + (size_t)node * H + m;
#pragma unroll
                    for (int ct = 0; ct < 8; ++ct)
                        hp[16 * ct] = fmaxf(c2[rt][ct][r], 0.f);
                }
            }
    } else {
#pragma unroll
        for (int rt = 0; rt < 2; ++rt)
#pragma unroll
            for (int r = 0; r < 4; ++r) {
                int node = nb + 16 * rt + 4 * g + r;
                if (node < n) {
                    unsigned short* hp = hbf + (size_t)node * H + m;
#pragma unroll
                    for (int ct = 0; ct < 8; ++ct)
                        hp[16 * ct] = f2bf(fmaxf(c2[rt][ct][r], 0.f));
                }
            }
    }
}

// ---------------- input proj (rank-1 first layer) + refine matmul + node emb, MFMA ----------------

__global__ __launch_bounds__(128) void input_proj_mfma_kernel(
    const float* __restrict__ nf,
    const float* __restrict__ W_in, const float* __restrict__ b_in,
    const unsigned short* __restrict__ WR, const float* __restrict__ b_ref,
    const float* __restrict__ node_emb,
    int n, unsigned short* __restrict__ hbf) {
    __shared__ float sx[64];
    __shared__ int sid[64];
    const int t = threadIdx.x;
    const int w = t >> 6, lane = t & 63;
    const int m = lane & 15, g = lane >> 4;
    const int nb0 = blockIdx.x * 64;
    if (t < 64) {
        int node = nb0 + t;
        float xv = (node < n) ? nf[node] : 0.f;
        sx[t] = fminf(fmaxf(xv / TWO48F, 0.f), 1.f);
        sid[t] = ((int)xv) & (NNODE_LBL - 1);
    }
    __syncthreads();
    const int nb = nb0 + w * 32;

    bf16x8 ta[2][4];
#pragma unroll
    for (int rt = 0; rt < 2; ++rt) {
        float xv = sx[w * 32 + 16 * rt + m];
#pragma unroll
        for (int ks = 0; ks < 4; ++ks) {
            float4 w0 = *(const float4*)(W_in + 32 * ks + 8 * g);
            float4 w1 = *(const float4*)(W_in + 32 * ks + 8 * g + 4);
            float4 b0 = *(const float4*)(b_in + 32 * ks + 8 * g);
            float4 b1 = *(const float4*)(b_in + 32 * ks + 8 * g + 4);
            bf16x8 v;
            v[0] = (short)f2bf(relu_f(fmaf(xv, w0.x, b0.x)));
            v[1] = (short)f2bf(relu_f(fmaf(xv, w0.y, b0.y)));
            v[2] = (short)f2bf(relu_f(fmaf(xv, w0.z, b0.z)));
            v[3] = (short)f2bf(relu_f(fmaf(xv, w0.w, b0.w)));
            v[4] = (short)f2bf(relu_f(fmaf(xv, w1.x, b1.x)));
            v[5] = (short)f2bf(relu_f(fmaf(xv, w1.y, b1.y)));
            v[6] = (short)f2bf(relu_f(fmaf(xv, w1.z, b1.z)));
            v[7] = (short)f2bf(relu_f(fmaf(xv, w1.w, b1.w)));
            ta[rt][ks] = v;
        }
    }

    f32x4 c2[2][8];
#pragma unroll
    for (int ct = 0; ct < 8; ++ct) {
        float bias = b_ref[16 * ct + m];
        c2[0][ct] = (f32x4){bias, bias, bias, bias};
        c2[1][ct] = c2[0][ct];
    }
#pragma unroll
    for (int ct = 0; ct < 8; ++ct) {
#pragma unroll
        for (int ks = 0; ks < 4; ++ks) {
            bf16x8 bh = *(const bf16x8*)(WR + (size_t)(16 * ct + m) * H + 32 * ks + 8 * g);
            c2[0][ct] = __builtin_amdgcn_mfma_f32_16x16x32_bf16(ta[0][ks], bh, c2[0][ct], 0, 0, 0);
            c2[1][ct] = __builtin_amdgcn_mfma_f32_16x16x32_bf16(ta[1][ks], bh, c2[1][ct], 0, 0, 0);
        }
    }

#pragma unroll
    for (int rt = 0; rt < 2; ++rt)
#pragma unroll
        for (int r = 0; r < 4; ++r) {
            int node = nb + 16 * rt + 4 * g + r;
            if (node < n) {
                int id = sid[w * 32 + 16 * rt + 4 * g + r];
                const float* ep = node_emb + (size_t)id * H + m;
                unsigned short* hp = hbf + (size_t)node * H + m;
#pragma unroll
                for (int ct = 0; ct < 8; ++ct)
                    hp[16 * ct] = f2bf(c2[rt][ct][r] + ep[16 * ct]);
            }
        }
}

// ---------------- host launcher ----------------

extern "C" void kernel_launch(void* const* d_in, const int* in_sizes, int n_in,
                              void* d_out, int out_size, void* d_ws, size_t ws_size,
                              hipStream_t stream) {
    const float* nf       = (const float*)d_in[0];
    const int*   eidx     = (const int*)d_in[1];
    const int*   eattr    = (const int*)d_in[2];
    const float* W_in     = (const float*)d_in[3];
    const float* b_in     = (const float*)d_in[4];
    const float* W_ref    = (const float*)d_in[5];
    const float* b_ref    = (const float*)d_in[6];
    const float* node_emb = (const float*)d_in[7];
    const float* edge_emb = (const float*)d_in[8];
    const float* Pe1      = (const float*)d_in[9];
    const float* be1      = (const float*)d_in[10];
    const float* Pe2      = (const float*)d_in[11];
    const float* be2      = (const float*)d_in[12];
    const float* W_lin    = (const float*)d_in[13];
    const float* b_lin    = (const float*)d_in[14];
    const float* W_a      = (const float*)d_in[15];
    const float* b_a      = (const float*)d_in[16];
    const float* W_b      = (const float*)d_in[17];
    const float* b_b      = (const float*)d_in[18];

    const int N = in_sizes[0];
    const int E = in_sizes[2];
    const int* src = eidx;
    const int* dst = eidx + E;
    const int nb = (N + SPAN - 1) / SPAN;     // 782 buckets
    const size_t EPAD = (size_t)E + (size_t)3 * SPAN * nb + 64;

    char* ws = (char*)d_ws;
    size_t off = 0;
    auto carve = [&](size_t bytes) -> void* {
        void* p = (void*)(ws + off);
        off = (off + bytes + 511) & ~(size_t)511;
        return p;
    };
    unsigned short* z      = (unsigned short*)carve((size_t)N * H * sizeof(unsigned short));
    unsigned short* hbf    = (unsigned short*)carve((size_t)N * H * sizeof(unsigned short));
    unsigned* ebuf  = (unsigned*)carve(EPAD * sizeof(unsigned));
    int*   sorted = (int*)carve(EPAD * sizeof(int));
    int*   rowptr = (int*)carve((size_t)(N + 1) * sizeof(int));
    int*   rowend = (int*)carve((size_t)N * sizeof(int));
    int*   bcnt   = (int*)carve((size_t)nb * sizeof(int));
    int*   bbase  = (int*)carve((size_t)(nb + 1) * sizeof(int));
    int*   gcur   = (int*)carve((size_t)nb * sizeof(int));
    float* el_tab = (float*)carve((size_t)LAYERS * ELROWS * H * sizeof(float));
    float* e_proj = (float*)carve((size_t)NLBL * ED * sizeof(float));
    unsigned short* wsp = (unsigned short*)carve((size_t)7 * H * H * sizeof(unsigned short));
    float* h_out = (float*)d_out;

    // weight prep (bf16, transposed to [col][k])
    split_weights_kernel<<<dim3(64, 7), 256, 0, stream>>>(W_ref, W_a, W_b, wsp);

    // CSR build: bucket hist -> slack scan -> partition -> place (computes rowptr+rowend)
    hipMemsetAsync(bcnt, 0, (size_t)nb * sizeof(int), stream);
    bucket_hist_kernel<<<512, 256, 0, stream>>>(dst, E, nb, bcnt);
    bucket_scan_kernel<<<1, MAXB, 0, stream>>>(bcnt, nb, bbase, gcur);
    partition_kernel<<<(E + 4095) / 4096, 256, 0, stream>>>(src, dst, eattr, E, nb, gcur, ebuf);
    place_kernel<<<nb, SPAN, 0, stream>>>(ebuf, bbase, gcur, N, rowptr, rowend, sorted);

    // edge feature tables (256 labels + sentinel row)
    edge_proj_kernel<<<NLBL, ED, 0, stream>>>(edge_emb, Pe1, be1, Pe2, be2, e_proj);
    el_tab_kernel<<<dim3(ELROWS, LAYERS), H, 0, stream>>>(e_proj, W_lin, b_lin, el_tab);

    // node path
    const int gridMM = (N + 63) / 64;
    input_proj_mfma_kernel<<<gridMM, 128, 0, stream>>>(
        nf, W_in, b_in, wsp, b_ref, node_emb, N, hbf);

    for (int l = 0; l < LAYERS; ++l) {
        gather_kernel<<<(N + 3) / 4, 256, 0, stream>>>(
            hbf, rowptr, rowend, sorted, el_tab + (size_t)l * ELROWS * H, N, z);
        mlp_mfma_kernel<<<gridMM, 128, 0, stream>>>(
            z,
            wsp + (size_t)(1 + l) * H * H, b_a + (size_t)l * H,
            wsp + (size_t)(4 + l) * H * H, b_b + (size_t)l * H,
            N, hbf, (l == LAYERS - 1) ? h_out : nullptr);
    }
}